// Round 6
// baseline (92.682 us; speedup 1.0000x reference)
//
#include <hip/hip_runtime.h>
#include <hip/hip_fp16.h>

#define NQ   13
#define DIM  8192
#define PI_F 3.14159265358979323846f
#define NT   512     // 8 waves/block; grid 512 -> 2 blocks/CU -> 4 waves/SIMD
#define NAMP 16      // amplitudes per thread (4-bit register window)

// fp16 state in LDS, global layout L(i) = i + 4*(i>>5) (half2 slots).
#define NSLOT 9216

// Pattern H: i = (g<<4)|j, g = t with bits 2,3 swapped (g bit k = i bit 4+k).
//   reg j bits 0..3 = i bits 0..3 (q12..q9); lane-xor masks {1,2,8} flip
//   t0,t1,t3 = i bits {4,5,6} (q8,q7,q6); i7=t2, i8=t4, i9=t5, i10..12=t6..8.
//   16 contiguous slots -> 4x b128 at the 8-dword/bank floor (conflict-free).
// Pattern L: i = (j<<9)|c, c = ((t&1)<<7)|(((t>>1)&1)<<8)|((t>>2)&0x7F)
//   (c bit k = i bit k). reg j bits 0..3 = i bits 9..12 (q3..q0); lane-xor
//   masks {1,2} flip t0,t1 = i bits {7,8} (q5,q4). 16x b32 at stride 576
//   slots, 2 lanes/bank (free per m136).
__device__ __forceinline__ int permH(int t) {
  return (t & 0x1F3) | (((t >> 3) & 1) << 2) | (((t >> 2) & 1) << 3);
}
__device__ __forceinline__ int permL(int t) {
  return ((t & 1) << 7) | (((t >> 1) & 1) << 8) | ((t >> 2) & 0x7F);
}
__device__ __forceinline__ int baseH(int g) { return 16 * g + 4 * (g >> 1); }
__device__ __forceinline__ int baseL(int c) { return c + 4 * (c >> 5); }

union F4H { float4 f; __half2 h[4]; };

__device__ __forceinline__ void rsincos(float x, float* s, float* c) {
  const float INV2PI = 0.15915494309189535f;
  const float TWOPI  = 6.283185307179586f;
  float r = x * INV2PI;
  r -= rintf(r);
  float ang = r * TWOPI;
  *s = __sinf(ang);
  *c = __cosf(ang);
}

// ---- fp32 helpers
__device__ __forceinline__ float2 f2fma(float s, float2 a, float2 b) {
  return make_float2(fmaf(s, a.x, b.x), fmaf(s, a.y, b.y));
}
__device__ __forceinline__ float2 f2add(float2 a, float2 b) {
  return make_float2(a.x + b.x, a.y + b.y);
}
__device__ __forceinline__ float2 f2sub(float2 a, float2 b) {
  return make_float2(a.x - b.x, a.y - b.y);
}
__device__ __forceinline__ float2 cphase(float2 v, float cs, float sn) {
  return make_float2(fmaf(cs, v.x, -sn * v.y), fmaf(cs, v.y, sn * v.x));
}
__device__ __forceinline__ float2 cmul(float2 a, float2 b) {
  return make_float2(fmaf(a.x, b.x, -a.y * b.y), fmaf(a.x, b.y, a.y * b.x));
}

// ---- VALU cross-lane partner, SAFE masks only:
//  1,2: quad_perm (R1/R3-verified). 8: row_ror:8 (xor-8 regardless of
//  rotate-direction convention, since +8 == -8 mod 16).
template<int MASK>
__device__ __forceinline__ __half2 partnerH(__half2 v) {
  union { __half2 h; int i; } u, r; u.h = v;
  if constexpr (MASK == 1)
    r.i = __builtin_amdgcn_update_dpp(u.i, u.i, 0xB1, 0xF, 0xF, false);
  else if constexpr (MASK == 2)
    r.i = __builtin_amdgcn_update_dpp(u.i, u.i, 0x4E, 0xF, 0xF, false);
  else
    r.i = __builtin_amdgcn_update_dpp(u.i, u.i, 0x128, 0xF, 0xF, false);
  return r.h;
}

// ---- LDS access, H pattern (4x b128)
__device__ __forceinline__ void loadHh(const __half2* __restrict__ sAmp, int g, __half2* amp) {
  const __half2* p = sAmp + baseH(g);
  #pragma unroll
  for (int k = 0; k < 4; k++) {
    F4H u; u.f = *reinterpret_cast<const float4*>(p + 4 * k);
    #pragma unroll
    for (int c = 0; c < 4; c++) amp[4 * k + c] = u.h[c];
  }
}
__device__ __forceinline__ void storeHh(__half2* __restrict__ sAmp, int g, const __half2* amp) {
  __half2* p = sAmp + baseH(g);
  #pragma unroll
  for (int k = 0; k < 4; k++) {
    F4H u;
    #pragma unroll
    for (int c = 0; c < 4; c++) u.h[c] = amp[4 * k + c];
    *reinterpret_cast<float4*>(p + 4 * k) = u.f;
  }
}
// ---- LDS access, L pattern (16x b32, stride 576 slots)
__device__ __forceinline__ void loadLh(const __half2* __restrict__ sAmp, int c, __half2* amp) {
  const __half2* p = sAmp + baseL(c);
  #pragma unroll
  for (int j = 0; j < NAMP; j++) amp[j] = p[576 * j];
}
__device__ __forceinline__ void storeLh(__half2* __restrict__ sAmp, int c, const __half2* amp) {
  __half2* p = sAmp + baseL(c);
  #pragma unroll
  for (int j = 0; j < NAMP; j++) p[576 * j] = amp[j];
}

// ---- fp32 register-bit gate math (shear rotation, exact)
template<int KB>
__device__ __forceinline__ void fwht_bit(float2* amp) {
  #pragma unroll
  for (int j = 0; j < NAMP; j++) if (!(j & (1 << KB))) {
    int j1 = j | (1 << KB);
    float2 a0 = amp[j], a1 = amp[j1];
    amp[j]  = f2add(a0, a1);
    amp[j1] = f2sub(a0, a1);
  }
}
template<int KB>
__device__ __forceinline__ void applyRy(float2* amp, float ta, float sa) {
  #pragma unroll
  for (int j = 0; j < NAMP; j++) if (!(j & (1 << KB))) {
    int j1 = j | (1 << KB);
    amp[j]  = f2fma(-ta, amp[j1], amp[j]);
    amp[j1] = f2fma( sa, amp[j],  amp[j1]);
    amp[j]  = f2fma(-ta, amp[j1], amp[j]);
  }
}

// ---- fp16 lane-bit gates (partner exchange; R1/R3-verified math)
// Ry: bit0 lane: a' = c*a - s*p ; bit1 lane: a' = c*a + s*p
template<int MASK>
__device__ __forceinline__ void laneRyH(__half2* amp, __half2 c2, __half2 spm) {
  #pragma unroll
  for (int j = 0; j < NAMP; j++) {
    __half2 p = partnerH<MASK>(amp[j]);
    amp[j] = __hfma2(spm, p, __hmul2(c2, amp[j]));
  }
}
// FWHT: bit0 lane: a' = a + p ; bit1 lane: a' = p - a  ->  a' = sgn*a + p
template<int MASK>
__device__ __forceinline__ void laneFwhtH(__half2* amp, __half2 sgn) {
  #pragma unroll
  for (int j = 0; j < NAMP; j++) {
    __half2 p = partnerH<MASK>(amp[j]);
    amp[j] = __hfma2(sgn, amp[j], p);
  }
}

// phase tree over the 4-bit register window. Pattern coordinate x is in
// i-bit order: PAT 0 (H): x=g, g bit k = i bit 4+k, window = i bits 0..3.
//              PAT 1 (L): x=c, c bit k = i bit k,   window = i bits 9..12.
template<int PAT>
__device__ __forceinline__ void buildTree(const float* __restrict__ w, float bias,
                                          int x, float* s) {
  float base = bias;
  constexpr int B0 = (PAT == 0) ? 4 : 0;
  #pragma unroll
  for (int k = 0; k < 9; k++) base += ((x >> k) & 1) ? w[B0 + k] : 0.0f;
  constexpr int W0 = (PAT == 0) ? 0 : 9;
  s[0] = base;
  #pragma unroll
  for (int k = 0; k < 4; k++) {
    float wp = w[W0 + k];
    #pragma unroll
    for (int m = 0; m < (1 << k); m++) s[m | (1 << k)] = s[m] + wp;
  }
}

// psi *= exp(i*phi(i)), phi = u + 0.5*(v^2 - A2); INIT writes unit phase
template<int PAT, bool INIT>
__device__ __forceinline__ void featureDiag(float2* amp,
                                            const float* __restrict__ wXp,
                                            const float* __restrict__ wAp,
                                            const float* __restrict__ consp, int x) {
  float u[NAMP], v[NAMP];
  buildTree<PAT>(wXp, consp[0], x, u);
  buildTree<PAT>(wAp, consp[1], x, v);
  float A2 = consp[2];
  #pragma unroll
  for (int j = 0; j < NAMP; j++) {
    float phi = u[j] + 0.5f * (v[j] * v[j] - A2);
    float sn, cs; rsincos(phi, &sn, &cs);
    if constexpr (INIT) amp[j] = make_float2(cs, sn);
    else                amp[j] = cphase(amp[j], cs, sn);
  }
}

// psi *= ENT(i)*exp(i*rho(i)): Rz_l + ENT diagonal in pattern PAT.
// ENT parity: pairs inside x (i-bit-adjacent by construction) ^ boundary
// pair ^ pairs inside the window (compile-time per j).
template<int PAT>
__device__ __forceinline__ void applyDiag(float2* amp,
                                          const float* __restrict__ wb,
                                          const float* __restrict__ eR,
                                          const float* __restrict__ eI,
                                          float bias, int x) {
  float base = bias;
  constexpr int B0 = (PAT == 0) ? 4 : 0;
  #pragma unroll
  for (int k = 0; k < 9; k++) base += ((x >> k) & 1) ? wb[B0 + k] : 0.0f;
  constexpr int W0 = (PAT == 0) ? 0 : 9;
  float2 c[16];
  { float sn, cs; rsincos(base, &sn, &cs); c[0] = make_float2(cs, sn); }
  #pragma unroll
  for (int k = 0; k < 4; k++) {
    float2 e = make_float2(eR[W0 + k], eI[W0 + k]);
    #pragma unroll
    for (int m = 0; m < (1 << k); m++) c[m | (1 << k)] = cmul(c[m], e);
  }
  const int st = __popc(x & (x >> 1)) & 1;
  const int tb = (PAT == 0) ? (x & 1) : ((x >> 8) & 1);   // i4 / i8
  #pragma unroll
  for (int j = 0; j < 16; j++) {
    int jb = (PAT == 0) ? ((j >> 3) & 1) : (j & 1);        // i3 / i9
    int sg = st ^ (jb & tb) ^ (__popc(j & (j >> 1)) & 1);
    float sgn = sg ? -1.0f : 1.0f;
    amp[j] = cphase(amp[j], c[j].x * sgn, c[j].y * sgn);
  }
}

// 3 fp16 lane gates of one layer in H: q8(m1), q7(m2), q6(m8)
__device__ __forceinline__ void laneGatesH(__half2* ampH,
                                           const __half2* __restrict__ hC2,
                                           const __half2* __restrict__ hS2,
                                           int g0, int lane) {
  { __half2 s2 = hS2[g0 + 8]; laneRyH<1>(ampH, hC2[g0 + 8], (lane & 1) ? s2 : __hneg2(s2)); }
  { __half2 s2 = hS2[g0 + 7]; laneRyH<2>(ampH, hC2[g0 + 7], (lane & 2) ? s2 : __hneg2(s2)); }
  { __half2 s2 = hS2[g0 + 6]; laneRyH<8>(ampH, hC2[g0 + 6], (lane & 8) ? s2 : __hneg2(s2)); }
}
// 2 fp16 lane gates of one layer in L: q5(m1), q4(m2)
__device__ __forceinline__ void laneGatesL(__half2* ampH,
                                           const __half2* __restrict__ hC2,
                                           const __half2* __restrict__ hS2,
                                           int g0, int lane) {
  { __half2 s2 = hS2[g0 + 5]; laneRyH<1>(ampH, hC2[g0 + 5], (lane & 1) ? s2 : __hneg2(s2)); }
  { __half2 s2 = hS2[g0 + 4]; laneRyH<2>(ampH, hC2[g0 + 4], (lane & 2) ? s2 : __hneg2(s2)); }
}

// (512,4): 8 waves/block, VGPR cap 128; grid 512 -> 2 blocks/CU = 4 waves/SIMD.
__global__ __launch_bounds__(NT, 4) void qc_kernel(
    const float* __restrict__ xin,
    const float* __restrict__ thin,
    const float* __restrict__ bin,
    float* __restrict__ out) {
  __shared__ alignas(16) __half2 sAmp[NSLOT];
  __shared__ float gTA[65], gSA[65];      // fp32 shear coeffs, l*13+qubit
  __shared__ __half2 hC2[65], hS2[65];    // fp16 rotation (c,c),(s,s), l*13+qubit
  __shared__ float gBbit[65];             // Rz b by [l*13 + bitpos], bitpos = 12-q
  __shared__ float eBr[65], eBi[65];      // cos(b), sin(b) by [l*13 + bitpos]
  __shared__ float wX[13], wA[13];        // -2x, -2a by bitpos
  __shared__ float cons[8];               // 0:X 1:A 2:A2 3..7:-0.5*sum b_l
  __shared__ float red[NT / 64];

  const int t = threadIdx.x;
  const int lane = t & 63;
  const int g = permH(t);
  const int cc = permL(t);
  const int b = blockIdx.x;

  if (t < NQ) {
    float xq = xin[b * NQ + t];
    float aq = PI_F - xq;
    wX[12 - t] = -2.0f * xq;
    wA[12 - t] = -2.0f * aq;
  }
  if (t < 65) {
    float av = thin[2 * t];
    float bv = thin[2 * t + 1];
    float ca = cosf(0.5f * av);
    float sa = sinf(0.5f * av);
    float ta = sa / (1.0f + ca);
    gTA[t] = ta;
    gSA[t] = sa;
    hC2[t] = __float2half2_rn(ca);
    hS2[t] = __float2half2_rn(sa);
    int l = t / NQ, q = t % NQ;
    int s = l * NQ + (12 - q);
    gBbit[s] = bv;
    eBr[s] = cosf(bv);
    eBi[s] = sinf(bv);
  }
  __syncthreads();
  if (t == 0) {
    float X = 0.f, A = 0.f, A2 = 0.f;
    for (int p = 0; p < NQ; p++) {
      float xq = -0.5f * wX[p], aq = -0.5f * wA[p];
      X += xq; A += aq; A2 += aq * aq;
    }
    cons[0] = X; cons[1] = A; cons[2] = A2;
    for (int l = 0; l < 5; l++) {
      float s = 0.f;
      for (int p = 0; p < NQ; p++) s += gBbit[l * NQ + p];
      cons[3 + l] = -0.5f * s;
    }
  }
  __syncthreads();

  const __half2 P1 = __float2half2_rn(1.0f), M1 = __float2half2_rn(-1.0f);

  // ---- S0 [H]: init psi = exp(i*phi1); FWHT i-bits 0..3 (reg fp32),
  //              4,5,6 (lane fp16, masks 1,2,8)
  {
    float2 ampF[NAMP];
    featureDiag<0, true>(ampF, wX, wA, cons, g);
    fwht_bit<0>(ampF); fwht_bit<1>(ampF); fwht_bit<2>(ampF); fwht_bit<3>(ampF);
    __half2 ampH[NAMP];
    #pragma unroll
    for (int j = 0; j < NAMP; j++) ampH[j] = __float22half2_rn(ampF[j]);
    laneFwhtH<1>(ampH, (lane & 1) ? M1 : P1);   // i bit 4
    laneFwhtH<2>(ampH, (lane & 2) ? M1 : P1);   // i bit 5
    laneFwhtH<8>(ampH, (lane & 8) ? M1 : P1);   // i bit 6
    storeHh(sAmp, g, ampH);
  }
  __syncthreads();

  // ---- S1 [L]: FWHT i-bits 7,8 (lane fp16), 9..12 (reg fp32); featDiag2;
  //              L0 gates: q3..q0 reg fp32, q5,q4 lane fp16
  {
    __half2 ampH[NAMP];
    loadLh(sAmp, cc, ampH);
    laneFwhtH<1>(ampH, (lane & 1) ? M1 : P1);   // i bit 7
    laneFwhtH<2>(ampH, (lane & 2) ? M1 : P1);   // i bit 8
    float2 ampF[NAMP];
    #pragma unroll
    for (int j = 0; j < NAMP; j++) ampF[j] = __half22float2(ampH[j]);
    fwht_bit<0>(ampF); fwht_bit<1>(ampF); fwht_bit<2>(ampF); fwht_bit<3>(ampF);
    featureDiag<1, false>(ampF, wX, wA, cons, cc);
    applyRy<0>(ampF, gTA[3], gSA[3]);   // qubit 3 (i bit 9)
    applyRy<1>(ampF, gTA[2], gSA[2]);   // qubit 2
    applyRy<2>(ampF, gTA[1], gSA[1]);   // qubit 1
    applyRy<3>(ampF, gTA[0], gSA[0]);   // qubit 0
    #pragma unroll
    for (int j = 0; j < NAMP; j++) ampH[j] = __float22half2_rn(ampF[j]);
    laneGatesL(ampH, hC2, hS2, 0, lane);        // q5, q4
    storeLh(sAmp, cc, ampH);
  }
  __syncthreads();

  // ---- S2/S4 [H] + S3/S5 [L]
  for (int l = 0; l < 4; l += 2) {
    const int ga = l * NQ, gb = ga + NQ, gc = gb + NQ;
    // H phase: layer l gates q12..q6, diag_l, layer l+1 gates q12..q6
    {
      __half2 ampH[NAMP];
      loadHh(sAmp, g, ampH);
      laneGatesH(ampH, hC2, hS2, ga, lane);
      float2 ampF[NAMP];
      #pragma unroll
      for (int j = 0; j < NAMP; j++) ampF[j] = __half22float2(ampH[j]);
      applyRy<0>(ampF, gTA[ga + 12], gSA[ga + 12]);
      applyRy<1>(ampF, gTA[ga + 11], gSA[ga + 11]);
      applyRy<2>(ampF, gTA[ga + 10], gSA[ga + 10]);
      applyRy<3>(ampF, gTA[ga + 9],  gSA[ga + 9]);
      applyDiag<0>(ampF, gBbit + ga, eBr + ga, eBi + ga, cons[3 + l], g);
      applyRy<0>(ampF, gTA[gb + 12], gSA[gb + 12]);
      applyRy<1>(ampF, gTA[gb + 11], gSA[gb + 11]);
      applyRy<2>(ampF, gTA[gb + 10], gSA[gb + 10]);
      applyRy<3>(ampF, gTA[gb + 9],  gSA[gb + 9]);
      #pragma unroll
      for (int j = 0; j < NAMP; j++) ampH[j] = __float22half2_rn(ampF[j]);
      laneGatesH(ampH, hC2, hS2, gb, lane);
      storeHh(sAmp, g, ampH);
    }
    __syncthreads();
    // L phase: layer l+1 gates q5..q0, diag_{l+1}, layer l+2 gates q5..q0
    {
      __half2 ampH[NAMP];
      loadLh(sAmp, cc, ampH);
      laneGatesL(ampH, hC2, hS2, gb, lane);
      float2 ampF[NAMP];
      #pragma unroll
      for (int j = 0; j < NAMP; j++) ampF[j] = __half22float2(ampH[j]);
      applyRy<0>(ampF, gTA[gb + 3], gSA[gb + 3]);
      applyRy<1>(ampF, gTA[gb + 2], gSA[gb + 2]);
      applyRy<2>(ampF, gTA[gb + 1], gSA[gb + 1]);
      applyRy<3>(ampF, gTA[gb + 0], gSA[gb + 0]);
      applyDiag<1>(ampF, gBbit + gb, eBr + gb, eBi + gb, cons[3 + l + 1], cc);
      applyRy<0>(ampF, gTA[gc + 3], gSA[gc + 3]);
      applyRy<1>(ampF, gTA[gc + 2], gSA[gc + 2]);
      applyRy<2>(ampF, gTA[gc + 1], gSA[gc + 1]);
      applyRy<3>(ampF, gTA[gc + 0], gSA[gc + 0]);
      #pragma unroll
      for (int j = 0; j < NAMP; j++) ampH[j] = __float22half2_rn(ampF[j]);
      laneGatesL(ampH, hC2, hS2, gc, lane);
      storeLh(sAmp, cc, ampH);
    }
    __syncthreads();
  }

  // ---- S6 [H]: layer 4 gates q12..q6; readout (trailing Rz_4 invisible)
  float acc = 0.0f;
  {
    const int ga = 4 * NQ;
    __half2 ampH[NAMP];
    loadHh(sAmp, g, ampH);
    laneGatesH(ampH, hC2, hS2, ga, lane);
    float2 ampF[NAMP];
    #pragma unroll
    for (int j = 0; j < NAMP; j++) ampF[j] = __half22float2(ampH[j]);
    applyRy<0>(ampF, gTA[ga + 12], gSA[ga + 12]);
    applyRy<1>(ampF, gTA[ga + 11], gSA[ga + 11]);
    applyRy<2>(ampF, gTA[ga + 10], gSA[ga + 10]);
    applyRy<3>(ampF, gTA[ga + 9],  gSA[ga + 9]);
    int pt = __popc(t) & 1;       // popc(g) == popc(t): g is a bit permutation
    #pragma unroll
    for (int j = 0; j < NAMP; j++) {
      float p2 = fmaf(ampF[j].x, ampF[j].x, ampF[j].y * ampF[j].y);
      acc += ((pt + __popc(j)) & 1) ? -p2 : p2;
    }
  }

  // block reduction (raw scale 2^26)
  #pragma unroll
  for (int off = 32; off > 0; off >>= 1) acc += __shfl_down(acc, off, 64);
  if ((t & 63) == 0) red[t >> 6] = acc;
  __syncthreads();
  if (t == 0) {
    float total = 0.f;
    #pragma unroll
    for (int w = 0; w < NT / 64; w++) total += red[w];
    float logit = total * (1.0f / 67108864.0f) + bin[0];
    out[b * 2 + 0] = -logit;
    out[b * 2 + 1] = logit;
  }
}

extern "C" void kernel_launch(void* const* d_in, const int* in_sizes, int n_in,
                              void* d_out, int out_size, void* d_ws, size_t ws_size,
                              hipStream_t stream) {
  const float* x  = (const float*)d_in[0];
  const float* th = (const float*)d_in[1];
  const float* bi = (const float*)d_in[2];
  float* out = (float*)d_out;
  int B = in_sizes[0] / NQ;   // 512
  qc_kernel<<<B, NT, 0, stream>>>(x, th, bi, out);
}

// Round 7
// 88.414 us; speedup vs baseline: 1.0483x; 1.0483x over previous
//
#include <hip/hip_runtime.h>
#include <hip/hip_fp16.h>

#define NQ   13
#define DIM  8192
#define PI_F 3.14159265358979323846f
#define NT   256     // 4 waves/block; grid 512 -> 2 blocks/CU
#define NAMP 32      // amplitudes per thread (5-bit register window)

// fp16 state in LDS, global layout L(i) = i + 4*(i>>5) (half2 slots).
#define NSLOT 9216

// Pattern H: i = (t<<5)|j. reg j bits 0..4 = i bits 0..4 (qubits 12..8);
//            lane bits 0,1 = i bits 5,6 (qubits 7,6) via DPP quad_perm.
//            Contiguous 32 slots -> 8x b128 (R3-verified conflict-free).
// Pattern L: i = (j<<8)|c, c = ((t&1)<<7)|((t&2)<<5)|(t>>2). reg j bits
//            0..4 = i bits 8..12 (qubits 4..0); lane bit 0 = i bit 7 (q5).
//            32x b32 at stride 288 slots (R3-verified 2 lanes/bank, free).
__device__ __forceinline__ int baseH(int t) { return 36 * t; }
__device__ __forceinline__ int baseL(int t) {
  int c = ((t & 1) << 7) | ((t & 2) << 5) | (t >> 2);
  return c + 4 * (c >> 5);
}

union F4H { float4 f; __half2 h[4]; };

__device__ __forceinline__ void rsincos(float x, float* s, float* c) {
  const float INV2PI = 0.15915494309189535f;
  const float TWOPI  = 6.283185307179586f;
  float r = x * INV2PI;
  r -= rintf(r);
  float ang = r * TWOPI;
  *s = __sinf(ang);
  *c = __cosf(ang);
}

// ---- fp32 helpers
__device__ __forceinline__ float2 f2add(float2 a, float2 b) {
  return make_float2(a.x + b.x, a.y + b.y);
}
__device__ __forceinline__ float2 f2sub(float2 a, float2 b) {
  return make_float2(a.x - b.x, a.y - b.y);
}
__device__ __forceinline__ float2 cphase(float2 v, float cs, float sn) {
  return make_float2(fmaf(cs, v.x, -sn * v.y), fmaf(cs, v.y, sn * v.x));
}
__device__ __forceinline__ float2 cmul(float2 a, float2 b) {
  return make_float2(fmaf(a.x, b.x, -a.y * b.y), fmaf(a.x, b.y, a.y * b.x));
}

// ---- DPP lane-xor (masks 1,2 only: quad_perm, pure VALU; R1/R3-verified)
template<int MASK>
__device__ __forceinline__ __half2 xorLaneH(__half2 v) {
  union { __half2 h; int i; } u, r; u.h = v;
  if constexpr (MASK == 1)
    r.i = __builtin_amdgcn_update_dpp(u.i, u.i, 0xB1, 0xF, 0xF, false);  // [1,0,3,2]
  else
    r.i = __builtin_amdgcn_update_dpp(u.i, u.i, 0x4E, 0xF, 0xF, false);  // [2,3,0,1]
  return r.h;
}

// ---- LDS access, H pattern (8x b128; R3-proven)
__device__ __forceinline__ void loadHh(const __half2* __restrict__ sAmp, int t, __half2* amp) {
  const __half2* p = sAmp + baseH(t);
  #pragma unroll
  for (int k = 0; k < 8; k++) {
    F4H u; u.f = *reinterpret_cast<const float4*>(p + 4 * k);
    #pragma unroll
    for (int c = 0; c < 4; c++) amp[4 * k + c] = u.h[c];
  }
}
__device__ __forceinline__ void storeHh(__half2* __restrict__ sAmp, int t, const __half2* amp) {
  __half2* p = sAmp + baseH(t);
  #pragma unroll
  for (int k = 0; k < 8; k++) {
    F4H u;
    #pragma unroll
    for (int c = 0; c < 4; c++) u.h[c] = amp[4 * k + c];
    *reinterpret_cast<float4*>(p + 4 * k) = u.f;
  }
}
// ---- LDS access, L pattern (32x b32, immediate offsets 288*j slots)
__device__ __forceinline__ void loadLh(const __half2* __restrict__ sAmp, int t, __half2* amp) {
  const __half2* p = sAmp + baseL(t);
  #pragma unroll
  for (int j = 0; j < NAMP; j++) amp[j] = p[288 * j];
}
__device__ __forceinline__ void storeLh(__half2* __restrict__ sAmp, int t, const __half2* amp) {
  __half2* p = sAmp + baseL(t);
  #pragma unroll
  for (int j = 0; j < NAMP; j++) p[288 * j] = amp[j];
}

// ---- fp32 register-bit FWHT (S0 only)
template<int KB>
__device__ __forceinline__ void fwht_bit(float2* amp) {
  #pragma unroll
  for (int j = 0; j < NAMP; j++) if (!(j & (1 << KB))) {
    int j1 = j | (1 << KB);
    float2 a0 = amp[j], a1 = amp[j1];
    amp[j]  = f2add(a0, a1);
    amp[j1] = f2sub(a0, a1);
  }
}
// ---- fp16 register-bit FWHT (S1; R0-verified)
template<int KB>
__device__ __forceinline__ void fwht_bitH(__half2* amp) {
  #pragma unroll
  for (int j = 0; j < NAMP; j++) if (!(j & (1 << KB))) {
    int j1 = j | (1 << KB);
    __half2 a0 = amp[j], a1 = amp[j1];
    amp[j]  = __hadd2(a0, a1);
    amp[j1] = __hsub2(a0, a1);
  }
}
// ---- fp16 register-bit Ry shear (R0-verified)
template<int KB>
__device__ __forceinline__ void applyRyH(__half2* amp, __half2 nta, __half2 sa) {
  #pragma unroll
  for (int j = 0; j < NAMP; j++) if (!(j & (1 << KB))) {
    int j1 = j | (1 << KB);
    amp[j]  = __hfma2(nta, amp[j1], amp[j]);
    amp[j1] = __hfma2(sa,  amp[j],  amp[j1]);
    amp[j]  = __hfma2(nta, amp[j1], amp[j]);
  }
}
// ---- fp16 DPP lane-bit gates (R1/R3-verified math)
template<int MASK>
__device__ __forceinline__ void laneRyH(__half2* amp, __half2 c2, __half2 spm) {
  #pragma unroll
  for (int j = 0; j < NAMP; j++) {
    __half2 p = xorLaneH<MASK>(amp[j]);
    amp[j] = __hfma2(spm, p, __hmul2(c2, amp[j]));
  }
}
template<int MASK>
__device__ __forceinline__ void laneFwhtH(__half2* amp, __half2 sgn) {
  #pragma unroll
  for (int j = 0; j < NAMP; j++) {
    __half2 p = xorLaneH<MASK>(amp[j]);
    amp[j] = __hfma2(sgn, amp[j], p);
  }
}

// phase tree over the 5-bit register window (R3-verified).
// PAT 0 (H): t bit k -> i bit 5+k -> w[5+k]; window bitpos {0,1,2,3,4}
// PAT 1 (L): t bits {0,1,2..7} -> i bits {7,6,0..5}; window bitpos {8..12}
template<int PAT>
__device__ __forceinline__ void buildTree(const float* __restrict__ w, float bias,
                                          int t, float* s) {
  float base = bias;
  if constexpr (PAT == 0) {
    #pragma unroll
    for (int k = 0; k < 8; k++) base += ((t >> k) & 1) ? w[5 + k] : 0.0f;
  } else {
    constexpr int BM[8] = {7, 6, 0, 1, 2, 3, 4, 5};
    #pragma unroll
    for (int k = 0; k < 8; k++) base += ((t >> k) & 1) ? w[BM[k]] : 0.0f;
  }
  s[0] = base;
  #pragma unroll
  for (int k = 0; k < 5; k++) {
    float wp = w[(PAT == 0) ? k : 8 + k];
    #pragma unroll
    for (int m = 0; m < (1 << k); m++) s[m | (1 << k)] = s[m] + wp;
  }
}

// psi *= exp(i*phi(i)), phi = u + 0.5*(v^2 - A2); INIT writes unit phase
template<int PAT, bool INIT>
__device__ __forceinline__ void featureDiag(float2* amp,
                                            const float* __restrict__ wXp,
                                            const float* __restrict__ wAp,
                                            const float* __restrict__ consp, int t) {
  float u[NAMP], v[NAMP];
  buildTree<PAT>(wXp, consp[0], t, u);
  buildTree<PAT>(wAp, consp[1], t, v);
  float A2 = consp[2];
  #pragma unroll
  for (int j = 0; j < NAMP; j++) {
    float phi = u[j] + 0.5f * (v[j] * v[j] - A2);
    float sn, cs; rsincos(phi, &sn, &cs);
    if constexpr (INIT) amp[j] = make_float2(cs, sn);
    else                amp[j] = cphase(amp[j], cs, sn);
  }
}

// psi *= ENT(i)*exp(i*rho(i)) in H (i=(t<<5)|j). ENT parity fully folded:
// thread pairs (i5..i12) -> c[0] sign; boundary (4,5)=j4&t0 -> e4 sign;
// window pairs (k-1,k) -> compile-time +/- on tree extension / e4 select.
__device__ __forceinline__ void applyDiagH(float2* amp,
                                           const float* __restrict__ wb,
                                           const float* __restrict__ eR,
                                           const float* __restrict__ eI,
                                           float bias, int t) {
  float base = bias;
  #pragma unroll
  for (int k = 0; k < 8; k++) base += ((t >> k) & 1) ? wb[5 + k] : 0.0f;
  float2 c[16];
  { float sn, cs; rsincos(base, &sn, &cs);
    float sg = (__popc(t & (t >> 1)) & 1) ? -1.0f : 1.0f;
    c[0] = make_float2(cs * sg, sn * sg); }
  #pragma unroll
  for (int k = 0; k < 4; k++) {
    float2 ep = make_float2(eR[k], eI[k]);
    float2 em = make_float2(-ep.x, -ep.y);
    #pragma unroll
    for (int m = 0; m < (1 << k); m++) {
      bool neg = (k >= 1) && ((m >> (k - 1)) & 1);   // window pair (k-1,k)
      c[m | (1 << k)] = cmul(c[m], neg ? em : ep);
    }
  }
  #pragma unroll
  for (int j = 0; j < 16; j++) amp[j] = cphase(amp[j], c[j].x, c[j].y);
  float2 e4 = make_float2(eR[4], eI[4]);
  if (t & 1) { e4.x = -e4.x; e4.y = -e4.y; }         // boundary (4,5)
  float2 e4m = make_float2(-e4.x, -e4.y);
  #pragma unroll
  for (int j = 16; j < 32; j++) {
    float2 cc = cmul(c[j - 16], ((j >> 3) & 1) ? e4m : e4);  // pair (3,4)
    amp[j] = cphase(amp[j], cc.x, cc.y);
  }
}

// psi *= ENT(i)*exp(i*rho(i)) in L (i=(j<<8)|c). Same folding:
// pairs inside c (i0..i7) -> c[0]; boundary (7,8)=c7&j0 -> e0 sign;
// window pairs (8,9),(9,10),(10,11) -> tree; (11,12) -> e4 select.
__device__ __forceinline__ void applyDiagL(float2* amp,
                                           const float* __restrict__ wb,
                                           const float* __restrict__ eR,
                                           const float* __restrict__ eI,
                                           float bias, int t) {
  constexpr int BM[8] = {7, 6, 0, 1, 2, 3, 4, 5};
  float base = bias;
  #pragma unroll
  for (int k = 0; k < 8; k++) base += ((t >> k) & 1) ? wb[BM[k]] : 0.0f;
  const int ci = ((t & 1) << 7) | ((t & 2) << 5) | (t >> 2);
  float2 c[16];
  { float sn, cs; rsincos(base, &sn, &cs);
    float sg = (__popc(ci & (ci >> 1)) & 1) ? -1.0f : 1.0f;
    c[0] = make_float2(cs * sg, sn * sg); }
  {
    float2 e0 = make_float2(eR[8], eI[8]);
    if (t & 1) { e0.x = -e0.x; e0.y = -e0.y; }       // boundary (7,8), c7 = t&1
    c[1] = cmul(c[0], e0);
  }
  #pragma unroll
  for (int k = 1; k < 4; k++) {
    float2 ep = make_float2(eR[8 + k], eI[8 + k]);
    float2 em = make_float2(-ep.x, -ep.y);
    #pragma unroll
    for (int m = 0; m < (1 << k); m++)
      c[m | (1 << k)] = cmul(c[m], ((m >> (k - 1)) & 1) ? em : ep);
  }
  #pragma unroll
  for (int j = 0; j < 16; j++) amp[j] = cphase(amp[j], c[j].x, c[j].y);
  float2 e4 = make_float2(eR[12], eI[12]);
  float2 e4m = make_float2(-e4.x, -e4.y);
  #pragma unroll
  for (int j = 16; j < 32; j++) {
    float2 cc = cmul(c[j - 16], ((j >> 3) & 1) ? e4m : e4);  // pair (11,12)
    amp[j] = cphase(amp[j], cc.x, cc.y);
  }
}

// H reg gates (q12..q8, window bits 0..4) + lane gates (q7 m1, q6 m2), fp16
__device__ __forceinline__ void gatesH(__half2* ampH,
                                       const __half2* __restrict__ hNTA,
                                       const __half2* __restrict__ hSA,
                                       const __half2* __restrict__ hC2,
                                       const __half2* __restrict__ hS2,
                                       int g0, int lane) {
  { __half2 s2 = hS2[g0 + 7]; laneRyH<1>(ampH, hC2[g0 + 7], (lane & 1) ? s2 : __hneg2(s2)); }
  { __half2 s2 = hS2[g0 + 6]; laneRyH<2>(ampH, hC2[g0 + 6], (lane & 2) ? s2 : __hneg2(s2)); }
  applyRyH<0>(ampH, hNTA[g0 + 12], hSA[g0 + 12]);
  applyRyH<1>(ampH, hNTA[g0 + 11], hSA[g0 + 11]);
  applyRyH<2>(ampH, hNTA[g0 + 10], hSA[g0 + 10]);
  applyRyH<3>(ampH, hNTA[g0 + 9],  hSA[g0 + 9]);
  applyRyH<4>(ampH, hNTA[g0 + 8],  hSA[g0 + 8]);
}
// L reg gates (q4..q0, window bits 0..4) + lane gate (q5 m1), fp16
__device__ __forceinline__ void gatesL(__half2* ampH,
                                       const __half2* __restrict__ hNTA,
                                       const __half2* __restrict__ hSA,
                                       const __half2* __restrict__ hC2,
                                       const __half2* __restrict__ hS2,
                                       int g0, int lane) {
  { __half2 s2 = hS2[g0 + 5]; laneRyH<1>(ampH, hC2[g0 + 5], (lane & 1) ? s2 : __hneg2(s2)); }
  applyRyH<0>(ampH, hNTA[g0 + 4], hSA[g0 + 4]);
  applyRyH<1>(ampH, hNTA[g0 + 3], hSA[g0 + 3]);
  applyRyH<2>(ampH, hNTA[g0 + 2], hSA[g0 + 2]);
  applyRyH<3>(ampH, hNTA[g0 + 1], hSA[g0 + 1]);
  applyRyH<4>(ampH, hNTA[g0 + 0], hSA[g0 + 0]);
}

// (256,1): lifted VGPR cap avoids the spill cliff; grid 512 -> 2 blocks/CU.
__global__ __launch_bounds__(NT, 1) void qc_kernel(
    const float* __restrict__ xin,
    const float* __restrict__ thin,
    const float* __restrict__ bin,
    float* __restrict__ out) {
  __shared__ alignas(16) __half2 sAmp[NSLOT];
  __shared__ __half2 hNTA[65], hSA[65];   // fp16 shear (-ta,-ta),(sa,sa), l*13+qubit
  __shared__ __half2 hC2[65], hS2[65];    // fp16 rotation (c,c),(s,s) for DPP gates
  __shared__ float gBbit[65];             // Rz b by [l*13 + bitpos], bitpos = 12-q
  __shared__ float eBr[65], eBi[65];      // cos(b), sin(b) by [l*13 + bitpos]
  __shared__ float wX[13], wA[13];        // -2x, -2a by bitpos
  __shared__ float cons[8];               // 0:X 1:A 2:A2 3..7:-0.5*sum b_l
  __shared__ float red[NT / 64];

  const int t = threadIdx.x;
  const int lane = t & 63;
  const int b = blockIdx.x;

  if (t < NQ) {
    float xq = xin[b * NQ + t];
    float aq = PI_F - xq;
    wX[12 - t] = -2.0f * xq;
    wA[12 - t] = -2.0f * aq;
  }
  if (t < 65) {
    float av = thin[2 * t];
    float bv = thin[2 * t + 1];
    float ca = cosf(0.5f * av);
    float sa = sinf(0.5f * av);
    float ta = sa / (1.0f + ca);
    hNTA[t] = __float2half2_rn(-ta);
    hSA[t]  = __float2half2_rn(sa);
    hC2[t]  = __float2half2_rn(ca);
    hS2[t]  = __float2half2_rn(sa);
    int l = t / NQ, q = t % NQ;
    int s = l * NQ + (12 - q);
    gBbit[s] = bv;
    eBr[s] = cosf(bv);
    eBi[s] = sinf(bv);
  }
  __syncthreads();
  if (t == 0) {
    float X = 0.f, A = 0.f, A2 = 0.f;
    for (int p = 0; p < NQ; p++) {
      float xq = -0.5f * wX[p], aq = -0.5f * wA[p];
      X += xq; A += aq; A2 += aq * aq;
    }
    cons[0] = X; cons[1] = A; cons[2] = A2;
    for (int l = 0; l < 5; l++) {
      float s = 0.f;
      for (int p = 0; p < NQ; p++) s += gBbit[l * NQ + p];
      cons[3 + l] = -0.5f * s;
    }
  }
  __syncthreads();

  const __half2 P1 = __float2half2_rn(1.0f), M1 = __float2half2_rn(-1.0f);

  // ---- S0 [H]: init psi = exp(i*phi1); FWHT i-bits 0..4 (reg fp32),
  //              5,6 (lane fp16, masks 1,2)
  {
    float2 ampF[NAMP];
    featureDiag<0, true>(ampF, wX, wA, cons, t);
    fwht_bit<0>(ampF); fwht_bit<1>(ampF); fwht_bit<2>(ampF);
    fwht_bit<3>(ampF); fwht_bit<4>(ampF);
    __half2 ampH[NAMP];
    #pragma unroll
    for (int j = 0; j < NAMP; j++) ampH[j] = __float22half2_rn(ampF[j]);
    laneFwhtH<1>(ampH, (lane & 1) ? M1 : P1);   // i bit 5
    laneFwhtH<2>(ampH, (lane & 2) ? M1 : P1);   // i bit 6
    storeHh(sAmp, t, ampH);
  }
  __syncthreads();

  // ---- S1 [L]: FWHT i-bit 7 (lane fp16), 8..12 (reg fp16); featDiag2 (fp32);
  //              L0 gates fp16 (q5 lane, q4..q0 reg)
  {
    __half2 ampH[NAMP];
    loadLh(sAmp, t, ampH);
    laneFwhtH<1>(ampH, (lane & 1) ? M1 : P1);   // i bit 7
    fwht_bitH<0>(ampH); fwht_bitH<1>(ampH); fwht_bitH<2>(ampH);
    fwht_bitH<3>(ampH); fwht_bitH<4>(ampH);     // i bits 8..12
    float2 ampF[NAMP];
    #pragma unroll
    for (int j = 0; j < NAMP; j++) ampF[j] = __half22float2(ampH[j]);
    featureDiag<1, false>(ampF, wX, wA, cons, t);
    #pragma unroll
    for (int j = 0; j < NAMP; j++) ampH[j] = __float22half2_rn(ampF[j]);
    gatesL(ampH, hNTA, hSA, hC2, hS2, 0, lane);
    storeLh(sAmp, t, ampH);
  }
  __syncthreads();

  // ---- S2/S4 [H] + S3/S5 [L]
  for (int l = 0; l < 4; l += 2) {
    const int ga = l * NQ, gb = ga + NQ, gc = gb + NQ;
    // H phase: layer l gates q12..q6 (fp16), diag_l (fp32), layer l+1 q12..q6
    {
      __half2 ampH[NAMP];
      loadHh(sAmp, t, ampH);
      gatesH(ampH, hNTA, hSA, hC2, hS2, ga, lane);
      float2 ampF[NAMP];
      #pragma unroll
      for (int j = 0; j < NAMP; j++) ampF[j] = __half22float2(ampH[j]);
      applyDiagH(ampF, gBbit + ga, eBr + ga, eBi + ga, cons[3 + l], t);
      #pragma unroll
      for (int j = 0; j < NAMP; j++) ampH[j] = __float22half2_rn(ampF[j]);
      gatesH(ampH, hNTA, hSA, hC2, hS2, gb, lane);
      storeHh(sAmp, t, ampH);
    }
    __syncthreads();
    // L phase: layer l+1 gates q5..q0 (fp16), diag_{l+1} (fp32), layer l+2
    {
      __half2 ampH[NAMP];
      loadLh(sAmp, t, ampH);
      gatesL(ampH, hNTA, hSA, hC2, hS2, gb, lane);
      float2 ampF[NAMP];
      #pragma unroll
      for (int j = 0; j < NAMP; j++) ampF[j] = __half22float2(ampH[j]);
      applyDiagL(ampF, gBbit + gb, eBr + gb, eBi + gb, cons[3 + l + 1], t);
      #pragma unroll
      for (int j = 0; j < NAMP; j++) ampH[j] = __float22half2_rn(ampF[j]);
      gatesL(ampH, hNTA, hSA, hC2, hS2, gc, lane);
      storeLh(sAmp, t, ampH);
    }
    __syncthreads();
  }

  // ---- S6 [H]: layer 4 gates q12..q6 (fp16); readout (trailing Rz invisible)
  float acc = 0.0f;
  {
    const int ga = 4 * NQ;
    __half2 ampH[NAMP];
    loadHh(sAmp, t, ampH);
    gatesH(ampH, hNTA, hSA, hC2, hS2, ga, lane);
    int pt = __popc(t) & 1;
    #pragma unroll
    for (int j = 0; j < NAMP; j++) {
      float2 a = __half22float2(ampH[j]);
      float p2 = fmaf(a.x, a.x, a.y * a.y);
      acc += ((pt + __popc(j)) & 1) ? -p2 : p2;
    }
  }

  // block reduction (raw scale 2^26)
  #pragma unroll
  for (int off = 32; off > 0; off >>= 1) acc += __shfl_down(acc, off, 64);
  if ((t & 63) == 0) red[t >> 6] = acc;
  __syncthreads();
  if (t == 0) {
    float total = red[0] + red[1] + red[2] + red[3];
    float logit = total * (1.0f / 67108864.0f) + bin[0];
    out[b * 2 + 0] = -logit;
    out[b * 2 + 1] = logit;
  }
}

extern "C" void kernel_launch(void* const* d_in, const int* in_sizes, int n_in,
                              void* d_out, int out_size, void* d_ws, size_t ws_size,
                              hipStream_t stream) {
  const float* x  = (const float*)d_in[0];
  const float* th = (const float*)d_in[1];
  const float* bi = (const float*)d_in[2];
  float* out = (float*)d_out;
  int B = in_sizes[0] / NQ;   // 512
  qc_kernel<<<B, NT, 0, stream>>>(x, th, bi, out);
}